// Round 5
// 2469.340 us; speedup vs baseline: 1.2383x; 1.2383x over previous
//
#include <hip/hip_runtime.h>

// Olmo3 MLP (no activation): y = down( (x@gate^T * gs) * (x@up^T * us) ) * ds
// H=4096, I=11008, M=B*S=8192. bf16 MFMA 16x16x32.
//
// R3 (fourth resubmit; R1-R4 benches were GPUAcquisitionTimeouts, no signal):
// 8-phase counted-vmcnt schedule (T2+T3+T4+T5 from the 256^2 template).
//  - gemm_down:   256x256 tile, BK=64, 8 waves (2Mx4N), LDS 128 KiB (2 dbuf).
//  - gemm_gateup: 256x128 tile, dual-B (gate+up share the A operand); LDS
//    2 x {A:32K, Bg:16K, Bu:16K} = 128 KiB. Identical phase structure.
//  Per K-tile: 4 phases, each {ds_read subtile || stage 1 half-tile ->
//  barrier -> setprio(1) 16 MFMA setprio(0) -> barrier}. Stage stream:
//  p1:(t+1).A1  p2:(t+2).B0  p3:(t+2).B1  p4:(t+2).A0; boundary vmcnt(6)
//  keeps 3 half-tiles in flight (never drains to 0 mid-loop).
//  Explicit lgkmcnt(0) at end of p3 drains the a[6,7] reads (consumed p4)
//  before p4 restages the A0 region.
//  Kept from R2: source-preswizzled LDS layout (phys chunk = kv ^ (row&7)),
//  measured conflict-free. Added: bijective XCD block swizzle (nwg%8==0).
//
// ws layout (~494 MiB):
//   [0,          64M)  x as bf16            [M,H]
//   [64M,       150M)  gate_w bf16          [I,H]
//   [150M,      236M)  up_w bf16            [I,H]
//   [236M,      322M)  down_w bf16          [H,I]
//   [322M,      494M)  t = g*u bf16         [M,I]

#define H_DIM 4096
#define I_DIM 11008
#define M_DIM 8192

typedef __bf16 bf16;
typedef __bf16 bf16x8 __attribute__((ext_vector_type(8)));
typedef float f32x4 __attribute__((ext_vector_type(4)));

#define GAS __attribute__((address_space(1)))
#define LAS __attribute__((address_space(3)))

__device__ __forceinline__ void async_ld16(const void* g, void* l) {
    __builtin_amdgcn_global_load_lds((const GAS void*)g, (LAS void*)l, 16, 0, 0);
}

__device__ __forceinline__ void barrier_f() {
    asm volatile("" ::: "memory");
    __builtin_amdgcn_s_barrier();
    asm volatile("" ::: "memory");
}

#define WAIT_LGKM0() asm volatile("s_waitcnt lgkmcnt(0)" ::: "memory")
#define WAIT_VM(N)   asm volatile("s_waitcnt vmcnt(" #N ")" ::: "memory")
#define MFMA16 __builtin_amdgcn_mfma_f32_16x16x32_bf16

// ---------------- prep: dtype conversion ----------------

__global__ __launch_bounds__(256) void cvt_i32_bf16_k(const int* __restrict__ src,
                                                      ushort* __restrict__ dst, int n4) {
    int t = blockIdx.x * 256 + threadIdx.x;
    if (t >= n4) return;
    const int4 v = ((const int4*)src)[t];
    ushort4 o;
    o.x = __builtin_bit_cast(ushort, (bf16)(float)v.x);
    o.y = __builtin_bit_cast(ushort, (bf16)(float)v.y);
    o.z = __builtin_bit_cast(ushort, (bf16)(float)v.z);
    o.w = __builtin_bit_cast(ushort, (bf16)(float)v.w);
    ((ushort4*)dst)[t] = o;
}

__global__ __launch_bounds__(256) void cvt_f32_bf16_k(const float* __restrict__ src,
                                                      ushort* __restrict__ dst, int n4) {
    int t = blockIdx.x * 256 + threadIdx.x;
    if (t >= n4) return;
    const float4 v = ((const float4*)src)[t];
    ushort4 o;
    o.x = __builtin_bit_cast(ushort, (bf16)v.x);
    o.y = __builtin_bit_cast(ushort, (bf16)v.y);
    o.z = __builtin_bit_cast(ushort, (bf16)v.z);
    o.w = __builtin_bit_cast(ushort, (bf16)v.w);
    ((ushort4*)dst)[t] = o;
}

// ---------------- fused gate+up GEMM, 256x128 tile, 8-phase ----------------
// LDS chunk map (16B units, per buf of 4096): A half h at h*1024 (128 rows x 8),
// Bg at 2048, Bu at 3072. buf base = (t&1)*4096.

__global__ __launch_bounds__(512, 2) void gemm_gateup(
    const bf16* __restrict__ X, const bf16* __restrict__ WG, const bf16* __restrict__ WU,
    const float* __restrict__ GS, const float* __restrict__ US, ushort* __restrict__ T) {
    __shared__ bf16x8 lds[8192];   // 128 KiB

    const int tid = threadIdx.x;
    const int lane = tid & 63;
    const int wave = tid >> 6;
    const int wm = wave >> 2, wn = wave & 3;

    // bijective XCD swizzle (nwg = 32*86 = 2752, %8==0)
    const int nx = gridDim.x;
    int lin = blockIdx.y * nx + blockIdx.x;
    const int q = (nx * gridDim.y) >> 3;
    lin = (lin & 7) * q + (lin >> 3);
    const int m0 = (lin % nx) * 256;
    const int i0 = (lin / nx) * 128;

    // staging source (pre-swizzled col chunk): row = tid>>3, phys chunk = tid&7
    const int srow = tid >> 3;
    const int scol = ((tid & 7) ^ (srow & 7)) * 8;
    const bf16* a_src = X  + (size_t)(m0 + srow) * H_DIM + scol;
    const bf16* g_src = WG + (size_t)(i0 + srow) * H_DIM + scol;
    const bf16* u_src = WU + (size_t)(i0 + srow) * H_DIM + scol;

    auto SA = [&](int kt, int h, int bb) {
        const bf16* s = a_src + (size_t)(h * 128) * H_DIM + kt * 64;
        async_ld16(s, &lds[bb + h * 1024 + tid]);
        async_ld16(s + (size_t)64 * H_DIM, &lds[bb + h * 1024 + 512 + tid]);
    };
    auto SG = [&](int kt, int bb) {
        const bf16* s = g_src + kt * 64;
        async_ld16(s, &lds[bb + 2048 + tid]);
        async_ld16(s + (size_t)64 * H_DIM, &lds[bb + 2048 + 512 + tid]);
    };
    auto SU = [&](int kt, int bb) {
        const bf16* s = u_src + kt * 64;
        async_ld16(s, &lds[bb + 3072 + tid]);
        async_ld16(s + (size_t)64 * H_DIM, &lds[bb + 3072 + 512 + tid]);
    };

    // read-side bases (16B chunk units); phys chunk = kv ^ (row&7), row&7 = lane&7
    const int l7 = lane & 7, kvh = lane >> 4;
    const int aix = (wm * 128 + (lane & 15)) * 8;
    const int gix = 2048 + (wn * 32 + (lane & 15)) * 8;
    const int uix = 3072 + (wn * 32 + (lane & 15)) * 8;

    f32x4 acc[8][4] = {};   // [mi][0..1]=gate cols, [mi][2..3]=up cols

    // prologue: tile0 {A0,A1,Bg,Bu} -> buf0; tile1 {Bg,Bu,A0} -> buf1
    SA(0, 0, 0); SA(0, 1, 0); SG(0, 0); SU(0, 0);
    SG(1, 4096); SU(1, 4096); SA(1, 0, 4096);
    WAIT_VM(6);
    barrier_f();

    const int NT = H_DIM / 64;   // 64
    for (int t = 0; t < NT; ++t) {
        const int cb = (t & 1) << 12;
        const int nb = cb ^ 4096;

        // ---- phase 1: read all B (8) + a[0,1] (4); stage (t+1).A1 ----
        bf16x8 b[4][2], a01[2][2];
#pragma unroll
        for (int j = 0; j < 2; ++j)
#pragma unroll
            for (int kk = 0; kk < 2; ++kk) {
                b[j][kk]     = lds[cb + gix + j * 128 + (((kk * 4 + kvh)) ^ l7)];
                b[2 + j][kk] = lds[cb + uix + j * 128 + (((kk * 4 + kvh)) ^ l7)];
            }
#pragma unroll
        for (int mi = 0; mi < 2; ++mi)
#pragma unroll
            for (int kk = 0; kk < 2; ++kk)
                a01[mi][kk] = lds[cb + aix + mi * 128 + (((kk * 4 + kvh)) ^ l7)];
        if (t + 1 < NT) SA(t + 1, 1, nb);
        barrier_f();
        __builtin_amdgcn_s_setprio(1);
#pragma unroll
        for (int mi = 0; mi < 2; ++mi)
#pragma unroll
            for (int j = 0; j < 4; ++j)
#pragma unroll
                for (int kk = 0; kk < 2; ++kk)
                    acc[mi][j] = MFMA16(a01[mi][kk], b[j][kk], acc[mi][j], 0, 0, 0);
        __builtin_amdgcn_s_setprio(0);
        barrier_f();

        // ---- phase 2: read a[2,3]; stage (t+2).Bg ----
        bf16x8 a23[2][2];
#pragma unroll
        for (int mi = 0; mi < 2; ++mi)
#pragma unroll
            for (int kk = 0; kk < 2; ++kk)
                a23[mi][kk] = lds[cb + aix + (2 + mi) * 128 + (((kk * 4 + kvh)) ^ l7)];
        if (t + 2 < NT) SG(t + 2, cb);
        barrier_f();
        __builtin_amdgcn_s_setprio(1);
#pragma unroll
        for (int mi = 0; mi < 2; ++mi)
#pragma unroll
            for (int j = 0; j < 4; ++j)
#pragma unroll
                for (int kk = 0; kk < 2; ++kk)
                    acc[2 + mi][j] = MFMA16(a23[mi][kk], b[j][kk], acc[2 + mi][j], 0, 0, 0);
        __builtin_amdgcn_s_setprio(0);
        barrier_f();

        // ---- phase 3: read a[4..7]; stage (t+2).Bu; MFMA a[4,5] ----
        bf16x8 a47[4][2];
#pragma unroll
        for (int mi = 0; mi < 4; ++mi)
#pragma unroll
            for (int kk = 0; kk < 2; ++kk)
                a47[mi][kk] = lds[cb + aix + (4 + mi) * 128 + (((kk * 4 + kvh)) ^ l7)];
        if (t + 2 < NT) SU(t + 2, cb);
        barrier_f();
        __builtin_amdgcn_s_setprio(1);
#pragma unroll
        for (int mi = 0; mi < 2; ++mi)
#pragma unroll
            for (int j = 0; j < 4; ++j)
#pragma unroll
                for (int kk = 0; kk < 2; ++kk)
                    acc[4 + mi][j] = MFMA16(a47[mi][kk], b[j][kk], acc[4 + mi][j], 0, 0, 0);
        __builtin_amdgcn_s_setprio(0);
        WAIT_LGKM0();   // drain a[6,7] reads before p4 restages A0
        barrier_f();

        // ---- phase 4: stage (t+2).A0; MFMA a[6,7]; counted vmcnt ----
        if (t + 2 < NT) SA(t + 2, 0, cb);
        barrier_f();
        __builtin_amdgcn_s_setprio(1);
#pragma unroll
        for (int mi = 0; mi < 2; ++mi)
#pragma unroll
            for (int j = 0; j < 4; ++j)
#pragma unroll
                for (int kk = 0; kk < 2; ++kk)
                    acc[6 + mi][j] = MFMA16(a47[2 + mi][kk], b[j][kk], acc[6 + mi][j], 0, 0, 0);
        __builtin_amdgcn_s_setprio(0);
        if (t + 2 < NT) { WAIT_VM(6); } else { WAIT_VM(0); }
        barrier_f();
    }

    // epilogue: C/D layout col=lane&15, row=(lane>>4)*4+r (m89-verified)
#pragma unroll
    for (int j = 0; j < 2; ++j) {
        const int col = i0 + wn * 32 + j * 16 + (lane & 15);
        const float gsv = GS[col], usv = US[col];
#pragma unroll
        for (int mi = 0; mi < 8; ++mi) {
            const int row0 = m0 + wm * 128 + mi * 16 + (lane >> 4) * 4;
#pragma unroll
            for (int r = 0; r < 4; ++r) {
                float g = acc[mi][j][r] * gsv;
                float u = acc[mi][2 + j][r] * usv;
                T[(size_t)(row0 + r) * I_DIM + col] = __builtin_bit_cast(ushort, (bf16)(g * u));
            }
        }
    }
}

// ---------------- down GEMM, 256x256 tile, 8-phase ----------------
// LDS chunk map (per buf of 4096): A half h at h*1024, B half h at 2048+h*1024.

__global__ __launch_bounds__(512, 2) void gemm_down(
    const bf16* __restrict__ T, const bf16* __restrict__ WD,
    const float* __restrict__ DS, float* __restrict__ Y) {
    __shared__ bf16x8 lds[8192];   // 128 KiB

    const int tid = threadIdx.x;
    const int lane = tid & 63;
    const int wave = tid >> 6;
    const int wm = wave >> 2, wn = wave & 3;

    // bijective XCD swizzle (nwg = 32*16 = 512, %8==0)
    const int nx = gridDim.x;
    int lin = blockIdx.y * nx + blockIdx.x;
    const int q = (nx * gridDim.y) >> 3;
    lin = (lin & 7) * q + (lin >> 3);
    const int m0 = (lin % nx) * 256;
    const int n0 = (lin / nx) * 256;

    const int srow = tid >> 3;
    const int scol = ((tid & 7) ^ (srow & 7)) * 8;
    const bf16* a_src = T  + (size_t)(m0 + srow) * I_DIM + scol;
    const bf16* b_src = WD + (size_t)(n0 + srow) * I_DIM + scol;

    auto SA = [&](int kt, int h, int bb) {
        const bf16* s = a_src + (size_t)(h * 128) * I_DIM + kt * 64;
        async_ld16(s, &lds[bb + h * 1024 + tid]);
        async_ld16(s + (size_t)64 * I_DIM, &lds[bb + h * 1024 + 512 + tid]);
    };
    auto SB = [&](int kt, int h, int bb) {
        const bf16* s = b_src + (size_t)(h * 128) * I_DIM + kt * 64;
        async_ld16(s, &lds[bb + 2048 + h * 1024 + tid]);
        async_ld16(s + (size_t)64 * I_DIM, &lds[bb + 2048 + h * 1024 + 512 + tid]);
    };

    const int l7 = lane & 7, kvh = lane >> 4;
    const int aix = (wm * 128 + (lane & 15)) * 8;
    const int bix = 2048 + ((wn >> 1) * 128 + (wn & 1) * 64 + (lane & 15)) * 8;

    f32x4 acc[8][4] = {};

    // prologue: tile0 {A0,A1,B0,B1} -> buf0; tile1 {B0,B1,A0} -> buf1
    SA(0, 0, 0); SA(0, 1, 0); SB(0, 0, 0); SB(0, 1, 0);
    SB(1, 0, 4096); SB(1, 1, 4096); SA(1, 0, 4096);
    WAIT_VM(6);
    barrier_f();

    const int NT = I_DIM / 64;   // 172
    for (int t = 0; t < NT; ++t) {
        const int cb = (t & 1) << 12;
        const int nb = cb ^ 4096;

        // ---- phase 1: read b[0..3] (8) + a[0,1] (4); stage (t+1).A1 ----
        bf16x8 b[4][2], a01[2][2];
#pragma unroll
        for (int j = 0; j < 4; ++j)
#pragma unroll
            for (int kk = 0; kk < 2; ++kk)
                b[j][kk] = lds[cb + bix + j * 128 + (((kk * 4 + kvh)) ^ l7)];
#pragma unroll
        for (int mi = 0; mi < 2; ++mi)
#pragma unroll
            for (int kk = 0; kk < 2; ++kk)
                a01[mi][kk] = lds[cb + aix + mi * 128 + (((kk * 4 + kvh)) ^ l7)];
        if (t + 1 < NT) SA(t + 1, 1, nb);
        barrier_f();
        __builtin_amdgcn_s_setprio(1);
#pragma unroll
        for (int mi = 0; mi < 2; ++mi)
#pragma unroll
            for (int j = 0; j < 4; ++j)
#pragma unroll
                for (int kk = 0; kk < 2; ++kk)
                    acc[mi][j] = MFMA16(a01[mi][kk], b[j][kk], acc[mi][j], 0, 0, 0);
        __builtin_amdgcn_s_setprio(0);
        barrier_f();

        // ---- phase 2: read a[2,3]; stage (t+2).B0 ----
        bf16x8 a23[2][2];
#pragma unroll
        for (int mi = 0; mi < 2; ++mi)
#pragma unroll
            for (int kk = 0; kk < 2; ++kk)
                a23[mi][kk] = lds[cb + aix + (2 + mi) * 128 + (((kk * 4 + kvh)) ^ l7)];
        if (t + 2 < NT) SB(t + 2, 0, cb);
        barrier_f();
        __builtin_amdgcn_s_setprio(1);
#pragma unroll
        for (int mi = 0; mi < 2; ++mi)
#pragma unroll
            for (int j = 0; j < 4; ++j)
#pragma unroll
                for (int kk = 0; kk < 2; ++kk)
                    acc[2 + mi][j] = MFMA16(a23[mi][kk], b[j][kk], acc[2 + mi][j], 0, 0, 0);
        __builtin_amdgcn_s_setprio(0);
        barrier_f();

        // ---- phase 3: read a[4..7]; stage (t+2).B1; MFMA a[4,5] ----
        bf16x8 a47[4][2];
#pragma unroll
        for (int mi = 0; mi < 4; ++mi)
#pragma unroll
            for (int kk = 0; kk < 2; ++kk)
                a47[mi][kk] = lds[cb + aix + (4 + mi) * 128 + (((kk * 4 + kvh)) ^ l7)];
        if (t + 2 < NT) SB(t + 2, 1, cb);
        barrier_f();
        __builtin_amdgcn_s_setprio(1);
#pragma unroll
        for (int mi = 0; mi < 2; ++mi)
#pragma unroll
            for (int j = 0; j < 4; ++j)
#pragma unroll
                for (int kk = 0; kk < 2; ++kk)
                    acc[4 + mi][j] = MFMA16(a47[mi][kk], b[j][kk], acc[4 + mi][j], 0, 0, 0);
        __builtin_amdgcn_s_setprio(0);
        WAIT_LGKM0();   // drain a[6,7] reads before p4 restages A0
        barrier_f();

        // ---- phase 4: stage (t+2).A0; MFMA a[6,7]; counted vmcnt ----
        if (t + 2 < NT) SA(t + 2, 0, cb);
        barrier_f();
        __builtin_amdgcn_s_setprio(1);
#pragma unroll
        for (int mi = 0; mi < 2; ++mi)
#pragma unroll
            for (int j = 0; j < 4; ++j)
#pragma unroll
                for (int kk = 0; kk < 2; ++kk)
                    acc[6 + mi][j] = MFMA16(a47[2 + mi][kk], b[j][kk], acc[6 + mi][j], 0, 0, 0);
        __builtin_amdgcn_s_setprio(0);
        if (t + 2 < NT) { WAIT_VM(6); } else { WAIT_VM(0); }
        barrier_f();
    }

#pragma unroll
    for (int j = 0; j < 4; ++j) {
        const int col = n0 + wn * 64 + j * 16 + (lane & 15);
        const float dsv = DS[col];
#pragma unroll
        for (int mi = 0; mi < 8; ++mi) {
            const int row0 = m0 + wm * 128 + mi * 16 + (lane >> 4) * 4;
#pragma unroll
            for (int r = 0; r < 4; ++r)
                Y[(size_t)(row0 + r) * H_DIM + col] = acc[mi][j][r] * dsv;
        }
    }
}

// ---------------- launch ----------------

extern "C" void kernel_launch(void* const* d_in, const int* in_sizes, int n_in,
                              void* d_out, int out_size, void* d_ws, size_t ws_size,
                              hipStream_t stream) {
    const float* x   = (const float*)d_in[0];
    const int*   gwq = (const int*)d_in[1];
    const float* gs  = (const float*)d_in[2];
    const int*   uwq = (const int*)d_in[3];
    const float* us  = (const float*)d_in[4];
    const int*   dwq = (const int*)d_in[5];
    const float* ds  = (const float*)d_in[6];
    float* y = (float*)d_out;

    char* ws = (char*)d_ws;
    bf16*   ws_x  = (bf16*)(ws);                              // 67,108,864 B
    bf16*   ws_gw = (bf16*)(ws + 67108864ull);                // 90,177,536 B
    bf16*   ws_uw = (bf16*)(ws + 157286400ull);               // 90,177,536 B
    bf16*   ws_dw = (bf16*)(ws + 247463936ull);               // 90,177,536 B
    ushort* ws_t  = (ushort*)(ws + 337641472ull);             // 180,355,072 B

    const int nx4 = M_DIM * H_DIM / 4;   // 8,388,608 -> 32768 blocks
    const int nw4 = I_DIM * H_DIM / 4;   // 11,272,192 -> 44032 blocks

    cvt_f32_bf16_k<<<nx4 / 256, 256, 0, stream>>>(x, (ushort*)ws_x, nx4);
    cvt_i32_bf16_k<<<nw4 / 256, 256, 0, stream>>>(gwq, (ushort*)ws_gw, nw4);
    cvt_i32_bf16_k<<<nw4 / 256, 256, 0, stream>>>(uwq, (ushort*)ws_uw, nw4);
    cvt_i32_bf16_k<<<nw4 / 256, 256, 0, stream>>>(dwq, (ushort*)ws_dw, nw4);

    gemm_gateup<<<dim3(M_DIM / 256, I_DIM / 128), 512, 0, stream>>>(ws_x, ws_gw, ws_uw, gs, us, ws_t);
    gemm_down<<<dim3(M_DIM / 256, H_DIM / 256), 512, 0, stream>>>((const bf16*)ws_t, ws_dw, ds, y);
}

// Round 7
// 2299.279 us; speedup vs baseline: 1.3299x; 1.0740x over previous
//
#include <hip/hip_runtime.h>

// Olmo3 MLP (no activation): y = down( (x@gate^T * gs) * (x@up^T * us) ) * ds
// H=4096, I=11008, M=B*S=8192. bf16 MFMA 16x16x32.
//
// R4 (resubmit; R6 bench was a GPUAcquisitionTimeout, no signal):
// R3's 8-phase counted-vmcnt schedule (verified: 1355us gateup, MfmaUtil
// 51%, 0 bank conflicts) + XCD-locality swizzle fix.
//  R3 counters showed FETCH_SIZE 3.0 GB vs 0.4 GB ideal: old swizzle gave
//  each XCD consecutive lin = all 32 m-tiles at one i0 -> 64 MB of distinct
//  A-panels live per XCD, X evicted from LLC by the T-write stream, staging
//  loads miss to HBM (~900cy) and overrun the 3-half-tile vmcnt pipeline.
//  New mapping: XCD k owns bx in {4k..4k+3} (32 bx / 8 XCDs = 4), sweeps by.
//  Concurrent per-XCD A working set = 1-2 panels (2 MB, L2-resident); the
//  by-window of weight panels is identical across XCDs (LLC-dedup, weights
//  stream ~once). d = by*nx+bx -> xcd=d&7, j=d>>3, bx=xcd*4+j/NBY, by=j%NBY
//  (bijective: 32x86 and 32x16 grids divide exactly).
//
//  Schedule (unchanged from R3): per K-tile 4 phases, each {ds_read subtile
//  || stage 1 half-tile -> barrier -> setprio(1) 16 MFMA setprio(0) ->
//  barrier}. Stage stream p1:(t+1).A1 p2:(t+2).B0 p3:(t+2).B1 p4:(t+2).A0;
//  boundary vmcnt(6) keeps 3 half-tiles in flight. lgkmcnt(0) at end of p3
//  drains a[6,7] reads before p4 restages A0. Source-preswizzled LDS layout
//  (phys chunk = kv ^ (row&7)), measured conflict-free.
//
// ws layout (~494 MiB):
//   [0,          64M)  x as bf16            [M,H]
//   [64M,       150M)  gate_w bf16          [I,H]
//   [150M,      236M)  up_w bf16            [I,H]
//   [236M,      322M)  down_w bf16          [H,I]
//   [322M,      494M)  t = g*u bf16         [M,I]

#define H_DIM 4096
#define I_DIM 11008
#define M_DIM 8192

typedef __bf16 bf16;
typedef __bf16 bf16x8 __attribute__((ext_vector_type(8)));
typedef float f32x4 __attribute__((ext_vector_type(4)));

#define GAS __attribute__((address_space(1)))
#define LAS __attribute__((address_space(3)))

__device__ __forceinline__ void async_ld16(const void* g, void* l) {
    __builtin_amdgcn_global_load_lds((const GAS void*)g, (LAS void*)l, 16, 0, 0);
}

__device__ __forceinline__ void barrier_f() {
    asm volatile("" ::: "memory");
    __builtin_amdgcn_s_barrier();
    asm volatile("" ::: "memory");
}

#define WAIT_LGKM0() asm volatile("s_waitcnt lgkmcnt(0)" ::: "memory")
#define WAIT_VM(N)   asm volatile("s_waitcnt vmcnt(" #N ")" ::: "memory")
#define MFMA16 __builtin_amdgcn_mfma_f32_16x16x32_bf16

// ---------------- prep: dtype conversion ----------------

__global__ __launch_bounds__(256) void cvt_i32_bf16_k(const int* __restrict__ src,
                                                      ushort* __restrict__ dst, int n4) {
    int t = blockIdx.x * 256 + threadIdx.x;
    if (t >= n4) return;
    const int4 v = ((const int4*)src)[t];
    ushort4 o;
    o.x = __builtin_bit_cast(ushort, (bf16)(float)v.x);
    o.y = __builtin_bit_cast(ushort, (bf16)(float)v.y);
    o.z = __builtin_bit_cast(ushort, (bf16)(float)v.z);
    o.w = __builtin_bit_cast(ushort, (bf16)(float)v.w);
    ((ushort4*)dst)[t] = o;
}

__global__ __launch_bounds__(256) void cvt_f32_bf16_k(const float* __restrict__ src,
                                                      ushort* __restrict__ dst, int n4) {
    int t = blockIdx.x * 256 + threadIdx.x;
    if (t >= n4) return;
    const float4 v = ((const float4*)src)[t];
    ushort4 o;
    o.x = __builtin_bit_cast(ushort, (bf16)v.x);
    o.y = __builtin_bit_cast(ushort, (bf16)v.y);
    o.z = __builtin_bit_cast(ushort, (bf16)v.z);
    o.w = __builtin_bit_cast(ushort, (bf16)v.w);
    ((ushort4*)dst)[t] = o;
}

// ---------------- fused gate+up GEMM, 256x128 tile, 8-phase ----------------
// LDS chunk map (16B units, per buf of 4096): A half h at h*1024 (128 rows x 8),
// Bg at 2048, Bu at 3072. buf base = (t&1)*4096.

__global__ __launch_bounds__(512, 2) void gemm_gateup(
    const bf16* __restrict__ X, const bf16* __restrict__ WG, const bf16* __restrict__ WU,
    const float* __restrict__ GS, const float* __restrict__ US, ushort* __restrict__ T) {
    __shared__ bf16x8 lds[8192];   // 128 KiB

    const int tid = threadIdx.x;
    const int lane = tid & 63;
    const int wave = tid >> 6;
    const int wm = wave >> 2, wn = wave & 3;

    // XCD-locality swizzle: XCD d&7 owns bx in {4k..4k+3}, sweeps by (i0).
    // grid 32(bx) x 86(by) = 2752; j/86 in [0,4), bijective.
    const int d = blockIdx.y * gridDim.x + blockIdx.x;
    const int xcd = d & 7, j = d >> 3;       // 344 blocks per XCD
    const int m0 = (xcd * 4 + j / 86) * 256;
    const int i0 = (j % 86) * 128;

    // staging source (pre-swizzled col chunk): row = tid>>3, phys chunk = tid&7
    const int srow = tid >> 3;
    const int scol = ((tid & 7) ^ (srow & 7)) * 8;
    const bf16* a_src = X  + (size_t)(m0 + srow) * H_DIM + scol;
    const bf16* g_src = WG + (size_t)(i0 + srow) * H_DIM + scol;
    const bf16* u_src = WU + (size_t)(i0 + srow) * H_DIM + scol;

    auto SA = [&](int kt, int h, int bb) {
        const bf16* s = a_src + (size_t)(h * 128) * H_DIM + kt * 64;
        async_ld16(s, &lds[bb + h * 1024 + tid]);
        async_ld16(s + (size_t)64 * H_DIM, &lds[bb + h * 1024 + 512 + tid]);
    };
    auto SG = [&](int kt, int bb) {
        const bf16* s = g_src + kt * 64;
        async_ld16(s, &lds[bb + 2048 + tid]);
        async_ld16(s + (size_t)64 * H_DIM, &lds[bb + 2048 + 512 + tid]);
    };
    auto SU = [&](int kt, int bb) {
        const bf16* s = u_src + kt * 64;
        async_ld16(s, &lds[bb + 3072 + tid]);
        async_ld16(s + (size_t)64 * H_DIM, &lds[bb + 3072 + 512 + tid]);
    };

    // read-side bases (16B chunk units); phys chunk = kv ^ (row&7), row&7 = lane&7
    const int l7 = lane & 7, kvh = lane >> 4;
    const int aix = (wm * 128 + (lane & 15)) * 8;
    const int gix = 2048 + (wn * 32 + (lane & 15)) * 8;
    const int uix = 3072 + (wn * 32 + (lane & 15)) * 8;

    f32x4 acc[8][4] = {};   // [mi][0..1]=gate cols, [mi][2..3]=up cols

    // prologue: tile0 {A0,A1,Bg,Bu} -> buf0; tile1 {Bg,Bu,A0} -> buf1
    SA(0, 0, 0); SA(0, 1, 0); SG(0, 0); SU(0, 0);
    SG(1, 4096); SU(1, 4096); SA(1, 0, 4096);
    WAIT_VM(6);
    barrier_f();

    const int NT = H_DIM / 64;   // 64
    for (int t = 0; t < NT; ++t) {
        const int cb = (t & 1) << 12;
        const int nb = cb ^ 4096;

        // ---- phase 1: read all B (8) + a[0,1] (4); stage (t+1).A1 ----
        bf16x8 b[4][2], a01[2][2];
#pragma unroll
        for (int j2 = 0; j2 < 2; ++j2)
#pragma unroll
            for (int kk = 0; kk < 2; ++kk) {
                b[j2][kk]     = lds[cb + gix + j2 * 128 + (((kk * 4 + kvh)) ^ l7)];
                b[2 + j2][kk] = lds[cb + uix + j2 * 128 + (((kk * 4 + kvh)) ^ l7)];
            }
#pragma unroll
        for (int mi = 0; mi < 2; ++mi)
#pragma unroll
            for (int kk = 0; kk < 2; ++kk)
                a01[mi][kk] = lds[cb + aix + mi * 128 + (((kk * 4 + kvh)) ^ l7)];
        if (t + 1 < NT) SA(t + 1, 1, nb);
        barrier_f();
        __builtin_amdgcn_s_setprio(1);
#pragma unroll
        for (int mi = 0; mi < 2; ++mi)
#pragma unroll
            for (int j2 = 0; j2 < 4; ++j2)
#pragma unroll
                for (int kk = 0; kk < 2; ++kk)
                    acc[mi][j2] = MFMA16(a01[mi][kk], b[j2][kk], acc[mi][j2], 0, 0, 0);
        __builtin_amdgcn_s_setprio(0);
        barrier_f();

        // ---- phase 2: read a[2,3]; stage (t+2).Bg ----
        bf16x8 a23[2][2];
#pragma unroll
        for (int mi = 0; mi < 2; ++mi)
#pragma unroll
            for (int kk = 0; kk < 2; ++kk)
                a23[mi][kk] = lds[cb + aix + (2 + mi) * 128 + (((kk * 4 + kvh)) ^ l7)];
        if (t + 2 < NT) SG(t + 2, cb);
        barrier_f();
        __builtin_amdgcn_s_setprio(1);
#pragma unroll
        for (int mi = 0; mi < 2; ++mi)
#pragma unroll
            for (int j2 = 0; j2 < 4; ++j2)
#pragma unroll
                for (int kk = 0; kk < 2; ++kk)
                    acc[2 + mi][j2] = MFMA16(a23[mi][kk], b[j2][kk], acc[2 + mi][j2], 0, 0, 0);
        __builtin_amdgcn_s_setprio(0);
        barrier_f();

        // ---- phase 3: read a[4..7]; stage (t+2).Bu; MFMA a[4,5] ----
        bf16x8 a47[4][2];
#pragma unroll
        for (int mi = 0; mi < 4; ++mi)
#pragma unroll
            for (int kk = 0; kk < 2; ++kk)
                a47[mi][kk] = lds[cb + aix + (4 + mi) * 128 + (((kk * 4 + kvh)) ^ l7)];
        if (t + 2 < NT) SU(t + 2, cb);
        barrier_f();
        __builtin_amdgcn_s_setprio(1);
#pragma unroll
        for (int mi = 0; mi < 2; ++mi)
#pragma unroll
            for (int j2 = 0; j2 < 4; ++j2)
#pragma unroll
                for (int kk = 0; kk < 2; ++kk)
                    acc[4 + mi][j2] = MFMA16(a47[mi][kk], b[j2][kk], acc[4 + mi][j2], 0, 0, 0);
        __builtin_amdgcn_s_setprio(0);
        WAIT_LGKM0();   // drain a[6,7] reads before p4 restages A0
        barrier_f();

        // ---- phase 4: stage (t+2).A0; MFMA a[6,7]; counted vmcnt ----
        if (t + 2 < NT) SA(t + 2, 0, cb);
        barrier_f();
        __builtin_amdgcn_s_setprio(1);
#pragma unroll
        for (int mi = 0; mi < 2; ++mi)
#pragma unroll
            for (int j2 = 0; j2 < 4; ++j2)
#pragma unroll
                for (int kk = 0; kk < 2; ++kk)
                    acc[6 + mi][j2] = MFMA16(a47[2 + mi][kk], b[j2][kk], acc[6 + mi][j2], 0, 0, 0);
        __builtin_amdgcn_s_setprio(0);
        if (t + 2 < NT) { WAIT_VM(6); } else { WAIT_VM(0); }
        barrier_f();
    }

    // epilogue: C/D layout col=lane&15, row=(lane>>4)*4+r (m89-verified)
#pragma unroll
    for (int j2 = 0; j2 < 2; ++j2) {
        const int col = i0 + wn * 32 + j2 * 16 + (lane & 15);
        const float gsv = GS[col], usv = US[col];
#pragma unroll
        for (int mi = 0; mi < 8; ++mi) {
            const int row0 = m0 + wm * 128 + mi * 16 + (lane >> 4) * 4;
#pragma unroll
            for (int r = 0; r < 4; ++r) {
                float g = acc[mi][j2][r] * gsv;
                float u = acc[mi][2 + j2][r] * usv;
                T[(size_t)(row0 + r) * I_DIM + col] = __builtin_bit_cast(ushort, (bf16)(g * u));
            }
        }
    }
}

// ---------------- down GEMM, 256x256 tile, 8-phase ----------------
// LDS chunk map (per buf of 4096): A half h at h*1024, B half h at 2048+h*1024.

__global__ __launch_bounds__(512, 2) void gemm_down(
    const bf16* __restrict__ T, const bf16* __restrict__ WD,
    const float* __restrict__ DS, float* __restrict__ Y) {
    __shared__ bf16x8 lds[8192];   // 128 KiB

    const int tid = threadIdx.x;
    const int lane = tid & 63;
    const int wave = tid >> 6;
    const int wm = wave >> 2, wn = wave & 3;

    // XCD-locality swizzle: XCD d&7 owns bx in {4k..4k+3}, sweeps by (n0).
    // grid 32(bx) x 16(by) = 512; j/16 in [0,4), bijective.
    const int d = blockIdx.y * gridDim.x + blockIdx.x;
    const int xcd = d & 7, j = d >> 3;       // 64 blocks per XCD
    const int m0 = (xcd * 4 + j / 16) * 256;
    const int n0 = (j % 16) * 256;

    const int srow = tid >> 3;
    const int scol = ((tid & 7) ^ (srow & 7)) * 8;
    const bf16* a_src = T  + (size_t)(m0 + srow) * I_DIM + scol;
    const bf16* b_src = WD + (size_t)(n0 + srow) * I_DIM + scol;

    auto SA = [&](int kt, int h, int bb) {
        const bf16* s = a_src + (size_t)(h * 128) * I_DIM + kt * 64;
        async_ld16(s, &lds[bb + h * 1024 + tid]);
        async_ld16(s + (size_t)64 * I_DIM, &lds[bb + h * 1024 + 512 + tid]);
    };
    auto SB = [&](int kt, int h, int bb) {
        const bf16* s = b_src + (size_t)(h * 128) * I_DIM + kt * 64;
        async_ld16(s, &lds[bb + 2048 + h * 1024 + tid]);
        async_ld16(s + (size_t)64 * I_DIM, &lds[bb + 2048 + h * 1024 + 512 + tid]);
    };

    const int l7 = lane & 7, kvh = lane >> 4;
    const int aix = (wm * 128 + (lane & 15)) * 8;
    const int bix = 2048 + ((wn >> 1) * 128 + (wn & 1) * 64 + (lane & 15)) * 8;

    f32x4 acc[8][4] = {};

    // prologue: tile0 {A0,A1,B0,B1} -> buf0; tile1 {B0,B1,A0} -> buf1
    SA(0, 0, 0); SA(0, 1, 0); SB(0, 0, 0); SB(0, 1, 0);
    SB(1, 0, 4096); SB(1, 1, 4096); SA(1, 0, 4096);
    WAIT_VM(6);
    barrier_f();

    const int NT = I_DIM / 64;   // 172
    for (int t = 0; t < NT; ++t) {
        const int cb = (t & 1) << 12;
        const int nb = cb ^ 4096;

        // ---- phase 1: read b[0..3] (8) + a[0,1] (4); stage (t+1).A1 ----
        bf16x8 b[4][2], a01[2][2];
#pragma unroll
        for (int j2 = 0; j2 < 4; ++j2)
#pragma unroll
            for (int kk = 0; kk < 2; ++kk)
                b[j2][kk] = lds[cb + bix + j2 * 128 + (((kk * 4 + kvh)) ^ l7)];
#pragma unroll
        for (int mi = 0; mi < 2; ++mi)
#pragma unroll
            for (int kk = 0; kk < 2; ++kk)
                a01[mi][kk] = lds[cb + aix + mi * 128 + (((kk * 4 + kvh)) ^ l7)];
        if (t + 1 < NT) SA(t + 1, 1, nb);
        barrier_f();
        __builtin_amdgcn_s_setprio(1);
#pragma unroll
        for (int mi = 0; mi < 2; ++mi)
#pragma unroll
            for (int j2 = 0; j2 < 4; ++j2)
#pragma unroll
                for (int kk = 0; kk < 2; ++kk)
                    acc[mi][j2] = MFMA16(a01[mi][kk], b[j2][kk], acc[mi][j2], 0, 0, 0);
        __builtin_amdgcn_s_setprio(0);
        barrier_f();

        // ---- phase 2: read a[2,3]; stage (t+2).B0 ----
        bf16x8 a23[2][2];
#pragma unroll
        for (int mi = 0; mi < 2; ++mi)
#pragma unroll
            for (int kk = 0; kk < 2; ++kk)
                a23[mi][kk] = lds[cb + aix + (2 + mi) * 128 + (((kk * 4 + kvh)) ^ l7)];
        if (t + 2 < NT) SB(t + 2, 0, cb);
        barrier_f();
        __builtin_amdgcn_s_setprio(1);
#pragma unroll
        for (int mi = 0; mi < 2; ++mi)
#pragma unroll
            for (int j2 = 0; j2 < 4; ++j2)
#pragma unroll
                for (int kk = 0; kk < 2; ++kk)
                    acc[2 + mi][j2] = MFMA16(a23[mi][kk], b[j2][kk], acc[2 + mi][j2], 0, 0, 0);
        __builtin_amdgcn_s_setprio(0);
        barrier_f();

        // ---- phase 3: read a[4..7]; stage (t+2).B1; MFMA a[4,5] ----
        bf16x8 a47[4][2];
#pragma unroll
        for (int mi = 0; mi < 4; ++mi)
#pragma unroll
            for (int kk = 0; kk < 2; ++kk)
                a47[mi][kk] = lds[cb + aix + (4 + mi) * 128 + (((kk * 4 + kvh)) ^ l7)];
        if (t + 2 < NT) SB(t + 2, 1, cb);
        barrier_f();
        __builtin_amdgcn_s_setprio(1);
#pragma unroll
        for (int mi = 0; mi < 2; ++mi)
#pragma unroll
            for (int j2 = 0; j2 < 4; ++j2)
#pragma unroll
                for (int kk = 0; kk < 2; ++kk)
                    acc[4 + mi][j2] = MFMA16(a47[mi][kk], b[j2][kk], acc[4 + mi][j2], 0, 0, 0);
        __builtin_amdgcn_s_setprio(0);
        WAIT_LGKM0();   // drain a[6,7] reads before p4 restages A0
        barrier_f();

        // ---- phase 4: stage (t+2).A0; MFMA a[6,7]; counted vmcnt ----
        if (t + 2 < NT) SA(t + 2, 0, cb);
        barrier_f();
        __builtin_amdgcn_s_setprio(1);
#pragma unroll
        for (int mi = 0; mi < 2; ++mi)
#pragma unroll
            for (int j2 = 0; j2 < 4; ++j2)
#pragma unroll
                for (int kk = 0; kk < 2; ++kk)
                    acc[6 + mi][j2] = MFMA16(a47[2 + mi][kk], b[j2][kk], acc[6 + mi][j2], 0, 0, 0);
        __builtin_amdgcn_s_setprio(0);
        if (t + 2 < NT) { WAIT_VM(6); } else { WAIT_VM(0); }
        barrier_f();
    }

#pragma unroll
    for (int j2 = 0; j2 < 4; ++j2) {
        const int col = n0 + wn * 64 + j2 * 16 + (lane & 15);
        const float dsv = DS[col];
#pragma unroll
        for (int mi = 0; mi < 8; ++mi) {
            const int row0 = m0 + wm * 128 + mi * 16 + (lane >> 4) * 4;
#pragma unroll
            for (int r = 0; r < 4; ++r)
                Y[(size_t)(row0 + r) * H_DIM + col] = acc[mi][j2][r] * dsv;
        }
    }
}

// ---------------- launch ----------------

extern "C" void kernel_launch(void* const* d_in, const int* in_sizes, int n_in,
                              void* d_out, int out_size, void* d_ws, size_t ws_size,
                              hipStream_t stream) {
    const float* x   = (const float*)d_in[0];
    const int*   gwq = (const int*)d_in[1];
    const float* gs  = (const float*)d_in[2];
    const int*   uwq = (const int*)d_in[3];
    const float* us  = (const float*)d_in[4];
    const int*   dwq = (const int*)d_in[5];
    const float* ds  = (const float*)d_in[6];
    float* y = (float*)d_out;

    char* ws = (char*)d_ws;
    bf16*   ws_x  = (bf16*)(ws);                              // 67,108,864 B
    bf16*   ws_gw = (bf16*)(ws + 67108864ull);                // 90,177,536 B
    bf16*   ws_uw = (bf16*)(ws + 157286400ull);               // 90,177,536 B
    bf16*   ws_dw = (bf16*)(ws + 247463936ull);               // 90,177,536 B
    ushort* ws_t  = (ushort*)(ws + 337641472ull);             // 180,355,072 B

    const int nx4 = M_DIM * H_DIM / 4;   // 8,388,608 -> 32768 blocks
    const int nw4 = I_DIM * H_DIM / 4;   // 11,272,192 -> 44032 blocks

    cvt_f32_bf16_k<<<nx4 / 256, 256, 0, stream>>>(x, (ushort*)ws_x, nx4);
    cvt_i32_bf16_k<<<nw4 / 256, 256, 0, stream>>>(gwq, (ushort*)ws_gw, nw4);
    cvt_i32_bf16_k<<<nw4 / 256, 256, 0, stream>>>(uwq, (ushort*)ws_uw, nw4);
    cvt_i32_bf16_k<<<nw4 / 256, 256, 0, stream>>>(dwq, (ushort*)ws_dw, nw4);

    gemm_gateup<<<dim3(M_DIM / 256, I_DIM / 128), 512, 0, stream>>>(ws_x, ws_gw, ws_uw, gs, us, ws_t);
    gemm_down<<<dim3(M_DIM / 256, H_DIM / 256), 512, 0, stream>>>((const bf16*)ws_t, ws_dw, ds, y);
}